// Round 4
// baseline (341.744 us; speedup 1.0000x reference)
//
#include <hip/hip_runtime.h>

typedef _Float16 f16;
typedef _Float16 f16x8 __attribute__((ext_vector_type(8)));
typedef _Float16 f16x4 __attribute__((ext_vector_type(4)));
typedef float f32x4 __attribute__((ext_vector_type(4)));
typedef float f32x16 __attribute__((ext_vector_type(16)));

#define LOG2E 1.44269504088896340736f
#define SOFF  36.0f   // fixed softmax offset (log2 domain); cancels exactly in sum(Pv)/sum(P)
#define CDIM 256
#define NPIX 4096

// async global->LDS 16B copy: lds dest = wave-uniform base + lane*16 (HW rule)
__device__ __forceinline__ void gl2lds16(const f16* g, const f16* l) {
    __builtin_amdgcn_global_load_lds((const __attribute__((address_space(1))) unsigned int*)g,
                                     (__attribute__((address_space(3))) unsigned int*)l, 16, 0, 0);
}

// ---------------- kernel 0: weights fp32 -> fp16 in MFMA A-frag layout ----------------
// WF[(ct*16+ks)*64 + lane][e] = W[ct*32+(lane&31)][ks*16+(lane>>5)*8+e]
__global__ void convert_w_kernel(const float* __restrict__ Wq, const float* __restrict__ Wk,
                                 const float* __restrict__ Wv,
                                 f16* __restrict__ WqF, f16* __restrict__ WkF,
                                 f16* __restrict__ WvF) {
    int t = blockIdx.x * 256 + threadIdx.x;   // 24576 threads: 3 matrices x 8192 groups
    int m = t >> 13;
    int g = t & 8191;
    int lane = g & 63;
    int ksct = g >> 6;                        // 0..127
    int ks = ksct & 15, ct = ksct >> 4;
    int o = ct * 32 + (lane & 31);
    int cin0 = ks * 16 + (lane >> 5) * 8;
    const float* W = (m == 0) ? Wq : ((m == 1) ? Wk : Wv);
    f16* WF = (m == 0) ? WqF : ((m == 1) ? WkF : WvF);
    const float scale = (m == 0) ? LOG2E : 1.0f;   // fold log2e into Wq
    const float* src = W + (size_t)o * CDIM + cin0;
    f16x8 v;
#pragma unroll
    for (int e = 0; e < 8; ++e) v[e] = (f16)(src[e] * scale);
    *(f16x8*)(WF + (size_t)g * 8) = v;
}

// ---------------- kernel 1: q/k/v projections, 48 MFMA 32x32x16 tiles per block -------
// qT,kT: [B][N][C] fp16 (row=pixel). vW: [B][C][N] fp16 (plain).
// NEW: A-frag software pipeline (ping-pong register buffers; next tile's 16 L2 loads
// issued before current tile's MFMAs) + even/odd split accumulator chains (halves the
// dependent-MFMA critical path). Outputs staged through wave-private 2KB LDS transpose.
__global__ __launch_bounds__(256, 2)
void proj_kernel(const float* __restrict__ x, const float* __restrict__ attr,
                 const f16* __restrict__ WqF, const float* __restrict__ bq,
                 const f16* __restrict__ WkF, const float* __restrict__ bk,
                 const f16* __restrict__ WvF, const float* __restrict__ bv,
                 f16* __restrict__ qT, f16* __restrict__ kT, f16* __restrict__ vW) {
    __shared__ __align__(16) f16 Xs[64 * 256];
    __shared__ __align__(16) f16 As[64 * 256];
    __shared__ __align__(16) f16 Ostage[4][1024];   // per-wave 2KB output transpose

    const int b  = blockIdx.x & 7;
    const int i0 = (blockIdx.x >> 3) * 64;
    const int t  = threadIdx.x;
    const int w = t >> 6, lane = t & 63, l31 = lane & 31, hi = lane >> 5;
    const int xu  = (l31 >> 1) & 15;          // 4-bit read-side XOR (chunk bits 1-4)
    const int hib = (hi ^ (l31 & 1)) * 8;     // chunk bit 0

    // stage transposed tiles: Xs[i][c] = x[b][c][i0+i]; phys chunk = chunk ^ (i&31)
    {
        const int i  = t & 63;
        const int cb = t >> 6;
        const float* xb = x    + (size_t)b * CDIM * NPIX + i0 + i;
        const float* ab = attr + (size_t)b * CDIM * NPIX + i0 + i;
#pragma unroll 2
        for (int rep = 0; rep < 8; ++rep) {
            int chunk = cb * 8 + rep;
            const float* xs = xb + (size_t)(chunk * 8) * NPIX;
            const float* as_ = ab + (size_t)(chunk * 8) * NPIX;
            f16x8 xv, av;
#pragma unroll
            for (int e = 0; e < 8; ++e) {
                xv[e] = (f16)xs[(size_t)e * NPIX];
                av[e] = (f16)as_[(size_t)e * NPIX];
            }
            int phys = chunk ^ (i & 31);
            *(f16x8*)(Xs + i * 256 + phys * 8) = xv;
            *(f16x8*)(As + i * 256 + phys * 8) = av;
        }
    }
    __syncthreads();

    // prefetch: issue all 16 A-frag global loads for tile k into af[]
    auto prefetch = [&](int k, f16x8* af) {
        const int tt = w + 4 * k;
        const int kind = tt >> 4;
        const int ct = (tt & 15) >> 1;
        const f16* WF = (kind == 0) ? WqF : ((kind == 1) ? WkF : WvF);
        const f16* ap = WF + (size_t)(ct * 16) * 512 + (size_t)lane * 8;
#pragma unroll
        for (int ks = 0; ks < 16; ++ks) af[ks] = *(const f16x8*)(ap + ks * 512);
    };

    // compute + store tile k using prefetched A-frags
    auto do_tile = [&](int k, const f16x8* af) {
        const int tt = w + 4 * k;
        const int kind = tt >> 4;          // 0=Q 1=K 2=V
        const int rr = tt & 15;
        const int ct = rr >> 1;
        const int half = rr & 1;

        const f16* Bs = (kind == 0) ? Xs : As;
        const float* bias = (kind == 0) ? bq : ((kind == 1) ? bk : bv);
        const float bscale = (kind == 0) ? LOG2E : 1.0f;
        const f16* bp = Bs + (half * 32 + l31) * 256 + hib;

        f32x16 ae, ao;                     // even/odd split chains (independent)
#pragma unroll
        for (int r = 0; r < 16; ++r) { ae[r] = 0.0f; ao[r] = 0.0f; }
#pragma unroll
        for (int h2 = 0; h2 < 8; ++h2) {
            f16x8 b0 = *(const f16x8*)(bp + (((2 * h2) ^ xu) << 4));
            f16x8 b1 = *(const f16x8*)(bp + (((2 * h2 + 1) ^ xu) << 4));
            ae = __builtin_amdgcn_mfma_f32_32x32x16_f16(af[2 * h2], b0, ae, 0, 0, 0);
            ao = __builtin_amdgcn_mfma_f32_32x32x16_f16(af[2 * h2 + 1], b1, ao, 0, 0, 0);
        }

        f16* st = Ostage[w];
        if (kind < 2) {
            // stage row-major [n32][c32]
#pragma unroll
            for (int g = 0; g < 4; ++g) {
                f32x4 bb = *(const f32x4*)(bias + ct * 32 + 4 * hi + 8 * g);
                f16x4 pk;
#pragma unroll
                for (int e = 0; e < 4; ++e)
                    pk[e] = (f16)(ae[4 * g + e] + ao[4 * g + e] + bb[e] * bscale);
                *(f16x4*)(st + l31 * 32 + 4 * hi + 8 * g) = pk;
            }
            // dump: 2 wave-stores, 16 rows x 64B dense segments each
            f16* dst = ((kind == 0) ? qT : kT)
                       + ((size_t)b * NPIX + i0 + half * 32) * CDIM + ct * 32;
#pragma unroll
            for (int d = 0; d < 2; ++d) {
                int row = d * 16 + (lane >> 2);
                int c8  = (lane & 3) * 8;
                f16x8 v = *(const f16x8*)(st + row * 32 + c8);
                *(f16x8*)(dst + (size_t)row * CDIM + c8) = v;
            }
        } else {
            // stage [c32][j32] (rows 64B), dump 16B chunks (lanes 0-3 = one 64B c-row)
#pragma unroll
            for (int g = 0; g < 4; ++g) {
                f32x4 bb = *(const f32x4*)(bias + ct * 32 + 4 * hi + 8 * g);
#pragma unroll
                for (int e = 0; e < 4; ++e) {
                    int c31 = 4 * hi + 8 * g + e;
                    st[c31 * 32 + l31] = (f16)(ae[4 * g + e] + ao[4 * g + e] + bb[e]);
                }
            }
            const int j0 = i0 + half * 32;
            f16* dstb = vW + (size_t)b * CDIM * NPIX + (size_t)(ct * 32) * NPIX + j0;
#pragma unroll
            for (int d = 0; d < 2; ++d) {
                int chunk = d * 64 + lane;          // 0..127
                int c31 = chunk >> 2, jch = chunk & 3;
                *(f16x8*)(dstb + (size_t)c31 * NPIX + jch * 8) =
                    *(const f16x8*)(st + chunk * 8);
            }
        }
    };

    f16x8 afA[16], afB[16];
    prefetch(0, afA);
#pragma unroll 1
    for (int k = 0; k < 12; k += 2) {
        prefetch(k + 1, afB);      // next tile's loads in flight over current MFMAs
        do_tile(k, afA);
        if (k < 10) prefetch(k + 2, afA);
        do_tile(k + 1, afB);
    }
}

// ---------------- kernel 2: flash attention + residual ----------------
// 512 threads = 8 waves = 4 i-strips x 2 j-halves; grid 256 = 1 block/CU.
// Double-buffered 2x(K 32KB + V 32KB) LDS; one barrier per iter; prefetch in flight
// across the compute phase. Full-width conflict-free LDS swizzles (R3, verified
// conflicts 16.8M->8.4M). setprio REMOVED (R3 regression: lockstep barrier structure,
// prio-1 MFMA waves starve prio-0 softmax waves' issue slots -- m190 mechanism).
__global__ __launch_bounds__(512, 2)
void attn_kernel(const f16* __restrict__ qT, const f16* __restrict__ kT,
                 const f16* __restrict__ vW, const float* __restrict__ x,
                 float* __restrict__ out) {
    extern __shared__ unsigned char smem[];   // 131584 B: 2x65536 buffers; epilogue overlay

    const int b    = blockIdx.x & 7;          // batch -> XCD pinning for K/V L2 reuse
    const int i0   = (blockIdx.x >> 3) * 128;
    const int t    = threadIdx.x;             // 0..511
    const int w    = t >> 6;
    const int lane = t & 63;
    const int l31  = lane & 31;
    const int hi   = lane >> 5;
    const int iw   = (w & 3) * 32;            // i-strip
    const int jh   = (w >> 2) * 32;           // j-half
    const int jh8  = (w >> 2) * 4;            // j-half in 8-col chunks
    const int ig   = i0 + iw + l31;

    // Q B-frags in registers: B[k=c][n=i], n = l31, k-offset 8*hi
    f16x8 qf[16];
    {
        const f16* qp = qT + ((size_t)b * NPIX + ig) * CDIM + hi * 8;
#pragma unroll
        for (int ks = 0; ks < 16; ++ks) qf[ks] = *(const f16x8*)(qp + ks * 16);
    }

    // K read addressing: phys chunk = (2*ks+hi) ^ l31  (row&31 == l31 for both j-halves)
    const int xu  = (l31 >> 1) & 15;                       // chunk bits 1-4
    const int kbase = (jh + l31) * 256 + (hi ^ (l31 & 1)) * 8;   // row + chunk bit 0
    // V read addressing: R = c>>2, p = ((c&3)<<3) | (jc ^ (c&7)); c = ct*32 + l31
    int vp2o[2];
    {
        int vbase = 16384 + (l31 >> 2) * 256 + (l31 & 3) * 64;
#pragma unroll
        for (int kj = 0; kj < 2; ++kj)
            vp2o[kj] = vbase + (((jh8 + 2 * kj + hi) ^ (l31 & 7))) * 8;
    }

    f32x16 acc[8];
#pragma unroll
    for (int ct = 0; ct < 8; ++ct)
#pragma unroll
        for (int r = 0; r < 16; ++r) acc[ct][r] = 0.0f;
    float lrun = 0.0f;

    const f16* kb = kT + (size_t)b * NPIX * CDIM;
    const f16* vb = vW + (size_t)b * CDIM * NPIX;
    f16* lds0 = (f16*)smem;
    const int wub = (t & ~63) * 8;            // wave-uniform staging base (f16 units)

    // prologue: stage tile 0 into buffer 0
    {
#pragma unroll
        for (int rep = 0; rep < 4; ++rep) {
            int slot = t + rep * 512;
            int krow = slot >> 5, kpc = slot & 31;
            gl2lds16(kb + (size_t)krow * CDIM + ((kpc ^ (krow & 31)) * 8),
                     lds0 + wub + rep * 4096);
            int R = slot >> 5, pv = slot & 31;
            int vc = 4 * R + (pv >> 3);
            int vjc = (pv & 7) ^ (vc & 7);
            gl2lds16(vb + (size_t)vc * NPIX + vjc * 8,
                     lds0 + 16384 + wub + rep * 4096);
        }
    }

    union Q4 { f16x4 h; unsigned int u[2]; };
    union B8 { f16x8 h; unsigned int u[4]; };

#pragma unroll 1
    for (int jt = 0; jt < 64; ++jt) {
        const int p = jt & 1;
        __syncthreads();   // drains vmcnt -> buffer p DMA complete; buffer p^1 free to restage

        if (jt < 63) {     // prefetch next tile into p^1; lands during this compute phase
            const int j0n = (jt + 1) * 64;
            f16* dstb = lds0 + (p ^ 1) * 32768;
#pragma unroll
            for (int rep = 0; rep < 4; ++rep) {
                int slot = t + rep * 512;
                int krow = slot >> 5, kpc = slot & 31;
                gl2lds16(kb + (size_t)(j0n + krow) * CDIM + ((kpc ^ (krow & 31)) * 8),
                         dstb + wub + rep * 4096);
                int R = slot >> 5, pv = slot & 31;
                int vc = 4 * R + (pv >> 3);
                int vjc = (pv & 7) ^ (vc & 7);
                gl2lds16(vb + (size_t)vc * NPIX + j0n + vjc * 8,
                         dstb + 16384 + wub + rep * 4096);
            }
        }

        const f16* L = lds0 + p * 32768;

        // S^T (32 j-half x 32 i) = K Q^T, C-init = -SOFF folds the exp2 offset
        f32x16 s;
#pragma unroll
        for (int r = 0; r < 16; ++r) s[r] = -SOFF;
#pragma unroll
        for (int ks = 0; ks < 16; ++ks)
            s = __builtin_amdgcn_mfma_f32_32x32x16_f16(
                *(const f16x8*)(L + kbase + ((ks ^ xu) << 4)), qf[ks], s, 0, 0, 0);

        // fixed-offset softmax numerator; row-sum accumulates in-register
        Q4 ownq[4];
        float rtot = 0.0f;
#pragma unroll
        for (int g = 0; g < 4; ++g) {
            float p0 = __builtin_amdgcn_exp2f(s[4 * g + 0]);
            float p1 = __builtin_amdgcn_exp2f(s[4 * g + 1]);
            float p2 = __builtin_amdgcn_exp2f(s[4 * g + 2]);
            float p3 = __builtin_amdgcn_exp2f(s[4 * g + 3]);
            rtot += (p0 + p1) + (p2 + p3);
            ownq[g].h[0] = (f16)p0; ownq[g].h[1] = (f16)p1;
            ownq[g].h[2] = (f16)p2; ownq[g].h[3] = (f16)p3;
        }
        lrun += rtot;

        // P: C-layout -> B-layout via lane^32 quad exchange
        f16x8 pb[2];
#pragma unroll
        for (int kj = 0; kj < 2; ++kj) {
            int sidx = 2 * kj + 1 - hi;
            int oidx = 2 * kj + hi;
            unsigned int s0 = ownq[sidx].u[0], s1 = ownq[sidx].u[1];
            unsigned int r0 = (unsigned int)__shfl_xor((int)s0, 32);
            unsigned int r1 = (unsigned int)__shfl_xor((int)s1, 32);
            B8 bb;
            bb.u[0] = hi ? r0 : ownq[oidx].u[0];
            bb.u[1] = hi ? r1 : ownq[oidx].u[1];
            bb.u[2] = hi ? ownq[oidx].u[0] : r0;
            bb.u[3] = hi ? ownq[oidx].u[1] : r1;
            pb[kj] = bb.h;
        }

        // O += V P^T
#pragma unroll
        for (int ct = 0; ct < 8; ++ct) {
            acc[ct] = __builtin_amdgcn_mfma_f32_32x32x16_f16(
                *(const f16x8*)(L + vp2o[0] + ct * 2048), pb[0], acc[ct], 0, 0, 0);
            acc[ct] = __builtin_amdgcn_mfma_f32_32x32x16_f16(
                *(const f16x8*)(L + vp2o[1] + ct * 2048), pb[1], acc[ct], 0, 0, 0);
        }
    }

    // ---- epilogue: merge j-half pairs (w <-> w+4), coalesced residual store ----
    float lsum = lrun + __shfl_xor(lrun, 32);
    __syncthreads();
    float* Obuf = (float*)smem;               // overlay: 4 x 8192 floats = 128 KB
    float* Ls   = (float*)(smem + 131072);    // 128 floats
    if (w >= 4) {
        float* ob = Obuf + (w - 4) * 8192;    // [c][i32]
#pragma unroll
        for (int ct = 0; ct < 8; ++ct)
#pragma unroll
            for (int r = 0; r < 16; ++r) {
                int c = ct * 32 + (r & 3) + 8 * (r >> 2) + 4 * hi;
                ob[c * 32 + l31] = acc[ct][r];
            }
        if (hi == 0) Ls[(w - 4) * 32 + l31] = lsum;
    }
    __syncthreads();
    if (w < 4) {
        const float ltot = lsum + Ls[w * 32 + l31];
        const float invl = 1.0f / ltot;
        const float* po = Obuf + w * 8192;
        const float* xb = x + (size_t)b * CDIM * NPIX + i0 + iw;
        float* og = out + (size_t)b * CDIM * NPIX + i0 + iw;
#pragma unroll
        for (int ct = 0; ct < 8; ++ct)
#pragma unroll
            for (int r = 0; r < 16; ++r) {
                int c = ct * 32 + (r & 3) + 8 * (r >> 2) + 4 * hi;
                size_t off = (size_t)c * NPIX + l31;
                og[off] = (acc[ct][r] + po[c * 32 + l31]) * invl + xb[off];
            }
    }
}

extern "C" void kernel_launch(void* const* d_in, const int* in_sizes, int n_in,
                              void* d_out, int out_size, void* d_ws, size_t ws_size,
                              hipStream_t stream) {
    const float* x    = (const float*)d_in[0];
    const float* attr = (const float*)d_in[1];
    const float* Wq   = (const float*)d_in[2];
    const float* bq   = (const float*)d_in[3];
    const float* Wk   = (const float*)d_in[4];
    const float* bk   = (const float*)d_in[5];
    const float* Wv   = (const float*)d_in[6];
    const float* bv   = (const float*)d_in[7];
    float* out = (float*)d_out;

    // workspace layout (~48.4 MB)
    char* ws = (char*)d_ws;
    const size_t qkv_bytes = (size_t)8 * NPIX * CDIM * sizeof(f16);  // 16 MB each
    f16* qT   = (f16*)ws;
    f16* kT   = (f16*)(ws + qkv_bytes);
    f16* vW   = (f16*)(ws + 2 * qkv_bytes);
    f16* WqF  = (f16*)(ws + 3 * qkv_bytes);
    f16* WkF  = WqF + 65536;
    f16* WvF  = WkF + 65536;

    (void)hipFuncSetAttribute((const void*)attn_kernel,
                              hipFuncAttributeMaxDynamicSharedMemorySize, 131584);

    convert_w_kernel<<<96, 256, 0, stream>>>(Wq, Wk, Wv, WqF, WkF, WvF);
    proj_kernel<<<512, 256, 0, stream>>>(x, attr, WqF, bq, WkF, bk, WvF, bv, qT, kT, vW);
    attn_kernel<<<256, 512, 131584, stream>>>(qT, kT, vW, x, out);
}

// Round 5
// 298.480 us; speedup vs baseline: 1.1449x; 1.1449x over previous
//
#include <hip/hip_runtime.h>

typedef _Float16 f16;
typedef _Float16 f16x8 __attribute__((ext_vector_type(8)));
typedef _Float16 f16x4 __attribute__((ext_vector_type(4)));
typedef float f32x4 __attribute__((ext_vector_type(4)));
typedef float f32x16 __attribute__((ext_vector_type(16)));

#define LOG2E 1.44269504088896340736f
#define SOFF  36.0f   // fixed softmax offset (log2 domain); cancels exactly in sum(Pv)/sum(P)
#define CDIM 256
#define NPIX 4096

// async global->LDS 16B copy: lds dest = wave-uniform base + lane*16 (HW rule)
__device__ __forceinline__ void gl2lds16(const f16* g, const f16* l) {
    __builtin_amdgcn_global_load_lds((const __attribute__((address_space(1))) unsigned int*)g,
                                     (__attribute__((address_space(3))) unsigned int*)l, 16, 0, 0);
}

// ---------------- kernel 0: weights fp32 -> fp16 in MFMA A-frag layout ----------------
// WF[(ct*16+ks)*64 + lane][e] = W[ct*32+(lane&31)][ks*16+(lane>>5)*8+e]
__global__ void convert_w_kernel(const float* __restrict__ Wq, const float* __restrict__ Wk,
                                 const float* __restrict__ Wv,
                                 f16* __restrict__ WqF, f16* __restrict__ WkF,
                                 f16* __restrict__ WvF) {
    int t = blockIdx.x * 256 + threadIdx.x;   // 24576 threads: 3 matrices x 8192 groups
    int m = t >> 13;
    int g = t & 8191;
    int lane = g & 63;
    int ksct = g >> 6;                        // 0..127
    int ks = ksct & 15, ct = ksct >> 4;
    int o = ct * 32 + (lane & 31);
    int cin0 = ks * 16 + (lane >> 5) * 8;
    const float* W = (m == 0) ? Wq : ((m == 1) ? Wk : Wv);
    f16* WF = (m == 0) ? WqF : ((m == 1) ? WkF : WvF);
    const float scale = (m == 0) ? LOG2E : 1.0f;   // fold log2e into Wq
    const float* src = W + (size_t)o * CDIM + cin0;
    f16x8 v;
#pragma unroll
    for (int e = 0; e < 8; ++e) v[e] = (f16)(src[e] * scale);
    *(f16x8*)(WF + (size_t)g * 8) = v;
}

// ---------------- kernel 1: q/k/v projections, 48 MFMA 32x32x16 tiles per block -------
// qT,kT: [B][N][C] fp16 (row=pixel). vW: [B][C][N] fp16 (plain).
// R3-proven version: A-frags from frag-layout WF (contiguous 1KB wave-loads); outputs
// staged through wave-private 2KB LDS transpose (dense wave-stores). No ping-pong
// (R4 showed the +32 live regs at 2 waves/SIMD cost more than the prefetch gained).
__global__ __launch_bounds__(256, 2)
void proj_kernel(const float* __restrict__ x, const float* __restrict__ attr,
                 const f16* __restrict__ WqF, const float* __restrict__ bq,
                 const f16* __restrict__ WkF, const float* __restrict__ bk,
                 const f16* __restrict__ WvF, const float* __restrict__ bv,
                 f16* __restrict__ qT, f16* __restrict__ kT, f16* __restrict__ vW) {
    __shared__ __align__(16) f16 Xs[64 * 256];
    __shared__ __align__(16) f16 As[64 * 256];
    __shared__ __align__(16) f16 Ostage[4][1024];   // per-wave 2KB output transpose

    const int b  = blockIdx.x & 7;
    const int i0 = (blockIdx.x >> 3) * 64;
    const int t  = threadIdx.x;
    const int w = t >> 6, lane = t & 63, l31 = lane & 31, hi = lane >> 5;
    const int xu  = (l31 >> 1) & 15;          // 4-bit read-side XOR (chunk bits 1-4)
    const int hib = (hi ^ (l31 & 1)) * 8;     // chunk bit 0

    // stage transposed tiles: Xs[i][c] = x[b][c][i0+i]; phys chunk = chunk ^ (i&31)
    {
        const int i  = t & 63;
        const int cb = t >> 6;
        const float* xb = x    + (size_t)b * CDIM * NPIX + i0 + i;
        const float* ab = attr + (size_t)b * CDIM * NPIX + i0 + i;
#pragma unroll 2
        for (int rep = 0; rep < 8; ++rep) {
            int chunk = cb * 8 + rep;
            const float* xs = xb + (size_t)(chunk * 8) * NPIX;
            const float* as_ = ab + (size_t)(chunk * 8) * NPIX;
            f16x8 xv, av;
#pragma unroll
            for (int e = 0; e < 8; ++e) {
                xv[e] = (f16)xs[(size_t)e * NPIX];
                av[e] = (f16)as_[(size_t)e * NPIX];
            }
            int phys = chunk ^ (i & 31);
            *(f16x8*)(Xs + i * 256 + phys * 8) = xv;
            *(f16x8*)(As + i * 256 + phys * 8) = av;
        }
    }
    __syncthreads();

#pragma unroll 1
    for (int k = 0; k < 12; ++k) {
        const int tt = w + 4 * k;          // wave-uniform
        const int kind = tt >> 4;          // 0=Q 1=K 2=V
        const int rr = tt & 15;
        const int ct = rr >> 1;
        const int half = rr & 1;

        const f16* WF = (kind == 0) ? WqF : ((kind == 1) ? WkF : WvF);
        const f16* Bs = (kind == 0) ? Xs : As;
        const float* bias = (kind == 0) ? bq : ((kind == 1) ? bk : bv);
        const float bscale = (kind == 0) ? LOG2E : 1.0f;

        // A-frags: contiguous 1KB per wave-load from frag-layout WF
        const f16* ap = WF + (size_t)(ct * 16) * 512 + (size_t)lane * 8;
        const f16* bp = Bs + (half * 32 + l31) * 256 + hib;

        f32x16 acc;
#pragma unroll
        for (int r = 0; r < 16; ++r) acc[r] = 0.0f;
#pragma unroll
        for (int ks = 0; ks < 16; ++ks) {
            f16x8 afr = *(const f16x8*)(ap + ks * 512);
            f16x8 bfr = *(const f16x8*)(bp + ((ks ^ xu) << 4));
            acc = __builtin_amdgcn_mfma_f32_32x32x16_f16(afr, bfr, acc, 0, 0, 0);
        }

        f16* st = Ostage[w];
        if (kind < 2) {
            // stage row-major [n32][c32]
#pragma unroll
            for (int g = 0; g < 4; ++g) {
                f32x4 bb = *(const f32x4*)(bias + ct * 32 + 4 * hi + 8 * g);
                f16x4 pk;
#pragma unroll
                for (int e = 0; e < 4; ++e) pk[e] = (f16)(acc[4 * g + e] + bb[e] * bscale);
                *(f16x4*)(st + l31 * 32 + 4 * hi + 8 * g) = pk;
            }
            // dump: 2 wave-stores, 16 rows x 64B dense segments each
            f16* dst = ((kind == 0) ? qT : kT)
                       + ((size_t)b * NPIX + i0 + half * 32) * CDIM + ct * 32;
#pragma unroll
            for (int d = 0; d < 2; ++d) {
                int row = d * 16 + (lane >> 2);
                int c8  = (lane & 3) * 8;
                f16x8 v = *(const f16x8*)(st + row * 32 + c8);
                *(f16x8*)(dst + (size_t)row * CDIM + c8) = v;
            }
        } else {
            // stage [c32][j32] (rows 64B), dump 16B chunks (lanes 0-3 = one 64B c-row)
#pragma unroll
            for (int g = 0; g < 4; ++g) {
                f32x4 bb = *(const f32x4*)(bias + ct * 32 + 4 * hi + 8 * g);
#pragma unroll
                for (int e = 0; e < 4; ++e) {
                    int c31 = 4 * hi + 8 * g + e;
                    st[c31 * 32 + l31] = (f16)(acc[4 * g + e] + bb[e]);
                }
            }
            const int j0 = i0 + half * 32;
            f16* dstb = vW + (size_t)b * CDIM * NPIX + (size_t)(ct * 32) * NPIX + j0;
#pragma unroll
            for (int d = 0; d < 2; ++d) {
                int chunk = d * 64 + lane;          // 0..127
                int c31 = chunk >> 2, jch = chunk & 3;
                *(f16x8*)(dstb + (size_t)c31 * NPIX + jch * 8) =
                    *(const f16x8*)(st + chunk * 8);
            }
        }
    }
}

// ---------------- kernel 2: flash attention + residual ----------------
// 512 threads = 8 waves = 4 i-strips x 2 j-halves; grid 256 = 1 block/CU.
// R0 structure verbatim (lean kp4o K addressing: 4 bases + ds_read immediates; 3-bit
// K swizzle — bank-equivalent to 5-bit, cheaper addressing). ONLY change vs R0:
// V layout/staging/read = R3's bijection (empirically removed V's 8.39M conflicts),
// same lean addressing shape (2 bases + ct*2048 immediates).
__global__ __launch_bounds__(512, 2)
void attn_kernel(const f16* __restrict__ qT, const f16* __restrict__ kT,
                 const f16* __restrict__ vW, const float* __restrict__ x,
                 float* __restrict__ out) {
    extern __shared__ unsigned char smem[];   // 131584 B: 2x65536 buffers; epilogue overlay

    const int b    = blockIdx.x & 7;          // batch -> XCD pinning for K/V L2 reuse
    const int i0   = (blockIdx.x >> 3) * 128;
    const int t    = threadIdx.x;             // 0..511
    const int w    = t >> 6;
    const int lane = t & 63;
    const int l31  = lane & 31;
    const int hi   = lane >> 5;
    const int iw   = (w & 3) * 32;            // i-strip
    const int jh   = (w >> 2) * 32;           // j-half
    const int jh8  = (w >> 2) * 4;            // j-half in 8-col chunks
    const int ig   = i0 + iw + l31;
    const int xorv = l31 & 7;

    // Q B-frags in registers: B[k=c][n=i], n = l31, k-offset 8*hi
    f16x8 qf[16];
    {
        const f16* qp = qT + ((size_t)b * NPIX + ig) * CDIM + hi * 8;
#pragma unroll
        for (int ks = 0; ks < 16; ++ks) qf[ks] = *(const f16x8*)(qp + ks * 16);
    }

    // K LDS frag offsets in f16 units, relative to buffer base (R0 verified swizzle)
    int kp4o[4];
    {
        int kboff = (jh + l31) * 256 + (hi ^ (xorv & 1)) * 8;
        const int xv2 = xorv >> 1;
#pragma unroll
        for (int r = 0; r < 4; ++r) kp4o[r] = kboff + (r ^ xv2) * 16;
    }
    // V read addressing (R3 bijection): R = c>>2, p = ((c&3)<<3) | (jc ^ (c&7));
    // c = ct*32 + l31, jc = jh8 + 2*kj + hi
    int vp2o[2];
    {
        int vbase = 16384 + (l31 >> 2) * 256 + (l31 & 3) * 64;
#pragma unroll
        for (int kj = 0; kj < 2; ++kj)
            vp2o[kj] = vbase + (((jh8 + 2 * kj + hi) ^ (l31 & 7))) * 8;
    }

    f32x16 acc[8];
#pragma unroll
    for (int ct = 0; ct < 8; ++ct)
#pragma unroll
        for (int r = 0; r < 16; ++r) acc[ct][r] = 0.0f;
    float lrun = 0.0f;

    const f16* kb = kT + (size_t)b * NPIX * CDIM;
    const f16* vb = vW + (size_t)b * CDIM * NPIX;
    f16* lds0 = (f16*)smem;
    const int wub = (t & ~63) * 8;            // wave-uniform staging base (f16 units)

    // prologue: stage tile 0 into buffer 0
    {
#pragma unroll
        for (int rep = 0; rep < 4; ++rep) {
            int slot = t + rep * 512;
            int krow = slot >> 5, kpc = slot & 31;
            gl2lds16(kb + (size_t)krow * CDIM + ((kpc ^ (krow & 7)) * 8),
                     lds0 + wub + rep * 4096);
            int R = slot >> 5, pv = slot & 31;
            int vc = 4 * R + (pv >> 3);
            int vjc = (pv & 7) ^ (vc & 7);
            gl2lds16(vb + (size_t)vc * NPIX + vjc * 8,
                     lds0 + 16384 + wub + rep * 4096);
        }
    }

    union Q4 { f16x4 h; unsigned int u[2]; };
    union B8 { f16x8 h; unsigned int u[4]; };

#pragma unroll 1
    for (int jt = 0; jt < 64; ++jt) {
        const int p = jt & 1;
        __syncthreads();   // drains vmcnt -> buffer p DMA complete; buffer p^1 free to restage

        if (jt < 63) {     // prefetch next tile into p^1; lands during this compute phase
            const int j0n = (jt + 1) * 64;
            f16* dstb = lds0 + (p ^ 1) * 32768;
#pragma unroll
            for (int rep = 0; rep < 4; ++rep) {
                int slot = t + rep * 512;
                int krow = slot >> 5, kpc = slot & 31;
                gl2lds16(kb + (size_t)(j0n + krow) * CDIM + ((kpc ^ (krow & 7)) * 8),
                         dstb + wub + rep * 4096);
                int R = slot >> 5, pv = slot & 31;
                int vc = 4 * R + (pv >> 3);
                int vjc = (pv & 7) ^ (vc & 7);
                gl2lds16(vb + (size_t)vc * NPIX + j0n + vjc * 8,
                         dstb + 16384 + wub + rep * 4096);
            }
        }

        const f16* L = lds0 + p * 32768;

        // S^T (32 j-half x 32 i) = K Q^T, C-init = -SOFF folds the exp2 offset
        f32x16 s;
#pragma unroll
        for (int r = 0; r < 16; ++r) s[r] = -SOFF;
#pragma unroll
        for (int ks = 0; ks < 16; ++ks)
            s = __builtin_amdgcn_mfma_f32_32x32x16_f16(
                *(const f16x8*)(L + kp4o[ks & 3] + (ks >> 2) * 64), qf[ks], s, 0, 0, 0);

        // fixed-offset softmax numerator; row-sum accumulates in-register
        Q4 ownq[4];
        float rtot = 0.0f;
#pragma unroll
        for (int g = 0; g < 4; ++g) {
            float p0 = __builtin_amdgcn_exp2f(s[4 * g + 0]);
            float p1 = __builtin_amdgcn_exp2f(s[4 * g + 1]);
            float p2 = __builtin_amdgcn_exp2f(s[4 * g + 2]);
            float p3 = __builtin_amdgcn_exp2f(s[4 * g + 3]);
            rtot += (p0 + p1) + (p2 + p3);
            ownq[g].h[0] = (f16)p0; ownq[g].h[1] = (f16)p1;
            ownq[g].h[2] = (f16)p2; ownq[g].h[3] = (f16)p3;
        }
        lrun += rtot;

        // P: C-layout -> B-layout via lane^32 quad exchange
        f16x8 pb[2];
#pragma unroll
        for (int kj = 0; kj < 2; ++kj) {
            int sidx = 2 * kj + 1 - hi;
            int oidx = 2 * kj + hi;
            unsigned int s0 = ownq[sidx].u[0], s1 = ownq[sidx].u[1];
            unsigned int r0 = (unsigned int)__shfl_xor((int)s0, 32);
            unsigned int r1 = (unsigned int)__shfl_xor((int)s1, 32);
            B8 bb;
            bb.u[0] = hi ? r0 : ownq[oidx].u[0];
            bb.u[1] = hi ? r1 : ownq[oidx].u[1];
            bb.u[2] = hi ? ownq[oidx].u[0] : r0;
            bb.u[3] = hi ? ownq[oidx].u[1] : r1;
            pb[kj] = bb.h;
        }

        // O += V P^T
#pragma unroll
        for (int ct = 0; ct < 8; ++ct) {
            acc[ct] = __builtin_amdgcn_mfma_f32_32x32x16_f16(
                *(const f16x8*)(L + vp2o[0] + ct * 2048), pb[0], acc[ct], 0, 0, 0);
            acc[ct] = __builtin_amdgcn_mfma_f32_32x32x16_f16(
                *(const f16x8*)(L + vp2o[1] + ct * 2048), pb[1], acc[ct], 0, 0, 0);
        }
    }

    // ---- epilogue: merge j-half pairs (w <-> w+4), coalesced residual store ----
    float lsum = lrun + __shfl_xor(lrun, 32);
    __syncthreads();
    float* Obuf = (float*)smem;               // overlay: 4 x 8192 floats = 128 KB
    float* Ls   = (float*)(smem + 131072);    // 128 floats
    if (w >= 4) {
        float* ob = Obuf + (w - 4) * 8192;    // [c][i32]
#pragma unroll
        for (int ct = 0; ct < 8; ++ct)
#pragma unroll
            for (int r = 0; r < 16; ++r) {
                int c = ct * 32 + (r & 3) + 8 * (r >> 2) + 4 * hi;
                ob[c * 32 + l31] = acc[ct][r];
            }
        if (hi == 0) Ls[(w - 4) * 32 + l31] = lsum;
    }
    __syncthreads();
    if (w < 4) {
        const float ltot = lsum + Ls[w * 32 + l31];
        const float invl = 1.0f / ltot;
        const float* po = Obuf + w * 8192;
        const float* xb = x + (size_t)b * CDIM * NPIX + i0 + iw;
        float* og = out + (size_t)b * CDIM * NPIX + i0 + iw;
#pragma unroll
        for (int ct = 0; ct < 8; ++ct)
#pragma unroll
            for (int r = 0; r < 16; ++r) {
                int c = ct * 32 + (r & 3) + 8 * (r >> 2) + 4 * hi;
                size_t off = (size_t)c * NPIX + l31;
                og[off] = (acc[ct][r] + po[c * 32 + l31]) * invl + xb[off];
            }
    }
}

extern "C" void kernel_launch(void* const* d_in, const int* in_sizes, int n_in,
                              void* d_out, int out_size, void* d_ws, size_t ws_size,
                              hipStream_t stream) {
    const float* x    = (const float*)d_in[0];
    const float* attr = (const float*)d_in[1];
    const float* Wq   = (const float*)d_in[2];
    const float* bq   = (const float*)d_in[3];
    const float* Wk   = (const float*)d_in[4];
    const float* bk   = (const float*)d_in[5];
    const float* Wv   = (const float*)d_in[6];
    const float* bv   = (const float*)d_in[7];
    float* out = (float*)d_out;

    // workspace layout (~48.4 MB)
    char* ws = (char*)d_ws;
    const size_t qkv_bytes = (size_t)8 * NPIX * CDIM * sizeof(f16);  // 16 MB each
    f16* qT   = (f16*)ws;
    f16* kT   = (f16*)(ws + qkv_bytes);
    f16* vW   = (f16*)(ws + 2 * qkv_bytes);
    f16* WqF  = (f16*)(ws + 3 * qkv_bytes);
    f16* WkF  = WqF + 65536;
    f16* WvF  = WkF + 65536;

    (void)hipFuncSetAttribute((const void*)attn_kernel,
                              hipFuncAttributeMaxDynamicSharedMemorySize, 131584);

    convert_w_kernel<<<96, 256, 0, stream>>>(Wq, Wk, Wv, WqF, WkF, WvF);
    proj_kernel<<<512, 256, 0, stream>>>(x, attr, WqF, bq, WkF, bk, WvF, bv, qT, kT, vW);
    attn_kernel<<<256, 512, 131584, stream>>>(qT, kT, vW, x, out);
}

// Round 6
// 296.102 us; speedup vs baseline: 1.1541x; 1.0080x over previous
//
#include <hip/hip_runtime.h>

typedef _Float16 f16;
typedef _Float16 f16x8 __attribute__((ext_vector_type(8)));
typedef _Float16 f16x4 __attribute__((ext_vector_type(4)));
typedef float f32x4 __attribute__((ext_vector_type(4)));
typedef float f32x16 __attribute__((ext_vector_type(16)));

#define LOG2E 1.44269504088896340736f
#define SOFF  36.0f   // fixed softmax offset (log2 domain); cancels exactly in sum(Pv)/sum(P)
#define CDIM 256
#define NPIX 4096

// async global->LDS 16B copy: lds dest = wave-uniform base + lane*16 (HW rule)
__device__ __forceinline__ void gl2lds16(const f16* g, const f16* l) {
    __builtin_amdgcn_global_load_lds((const __attribute__((address_space(1))) unsigned int*)g,
                                     (__attribute__((address_space(3))) unsigned int*)l, 16, 0, 0);
}

// ---------------- kernel 0: weights fp32 -> fp16 in MFMA A-frag layout ----------------
// WF[(ct*16+ks)*64 + lane][e] = W[ct*32+(lane&31)][ks*16+(lane>>5)*8+e]
__global__ void convert_w_kernel(const float* __restrict__ Wq, const float* __restrict__ Wk,
                                 const float* __restrict__ Wv,
                                 f16* __restrict__ WqF, f16* __restrict__ WkF,
                                 f16* __restrict__ WvF) {
    int t = blockIdx.x * 256 + threadIdx.x;   // 24576 threads: 3 matrices x 8192 groups
    int m = t >> 13;
    int g = t & 8191;
    int lane = g & 63;
    int ksct = g >> 6;                        // 0..127
    int ks = ksct & 15, ct = ksct >> 4;
    int o = ct * 32 + (lane & 31);
    int cin0 = ks * 16 + (lane >> 5) * 8;
    const float* W = (m == 0) ? Wq : ((m == 1) ? Wk : Wv);
    f16* WF = (m == 0) ? WqF : ((m == 1) ? WkF : WvF);
    const float scale = (m == 0) ? LOG2E : 1.0f;   // fold log2e into Wq
    const float* src = W + (size_t)o * CDIM + cin0;
    f16x8 v;
#pragma unroll
    for (int e = 0; e < 8; ++e) v[e] = (f16)(src[e] * scale);
    *(f16x8*)(WF + (size_t)g * 8) = v;
}

// ---------------- kernel 1: q/k/v projections, 48 MFMA 32x32x16 tiles per block -------
// qT: [B][N][C] fp16 (row=pixel). kC: chunk-major [B][kc 0..31][j 0..4095][8 f16]
// (so attn's j-contiguous LDS staging reads are coalesced). vW: [B][C][N] fp16.
// A-frags from frag-layout WF (contiguous 1KB wave-loads); outputs staged through a
// wave-private 2KB LDS transpose (dense wave-stores).
__global__ __launch_bounds__(256, 2)
void proj_kernel(const float* __restrict__ x, const float* __restrict__ attr,
                 const f16* __restrict__ WqF, const float* __restrict__ bq,
                 const f16* __restrict__ WkF, const float* __restrict__ bk,
                 const f16* __restrict__ WvF, const float* __restrict__ bv,
                 f16* __restrict__ qT, f16* __restrict__ kC, f16* __restrict__ vW) {
    __shared__ __align__(16) f16 Xs[64 * 256];
    __shared__ __align__(16) f16 As[64 * 256];
    __shared__ __align__(16) f16 Ostage[4][1024];   // per-wave 2KB output transpose

    const int b  = blockIdx.x & 7;
    const int i0 = (blockIdx.x >> 3) * 64;
    const int t  = threadIdx.x;
    const int w = t >> 6, lane = t & 63, l31 = lane & 31, hi = lane >> 5;
    const int xu  = (l31 >> 1) & 15;          // 4-bit read-side XOR (chunk bits 1-4)
    const int hib = (hi ^ (l31 & 1)) * 8;     // chunk bit 0

    // stage transposed tiles: Xs[i][c] = x[b][c][i0+i]; phys chunk = chunk ^ (i&31)
    {
        const int i  = t & 63;
        const int cb = t >> 6;
        const float* xb = x    + (size_t)b * CDIM * NPIX + i0 + i;
        const float* ab = attr + (size_t)b * CDIM * NPIX + i0 + i;
#pragma unroll 2
        for (int rep = 0; rep < 8; ++rep) {
            int chunk = cb * 8 + rep;
            const float* xs = xb + (size_t)(chunk * 8) * NPIX;
            const float* as_ = ab + (size_t)(chunk * 8) * NPIX;
            f16x8 xv, av;
#pragma unroll
            for (int e = 0; e < 8; ++e) {
                xv[e] = (f16)xs[(size_t)e * NPIX];
                av[e] = (f16)as_[(size_t)e * NPIX];
            }
            int phys = chunk ^ (i & 31);
            *(f16x8*)(Xs + i * 256 + phys * 8) = xv;
            *(f16x8*)(As + i * 256 + phys * 8) = av;
        }
    }
    __syncthreads();

#pragma unroll 1
    for (int k = 0; k < 12; ++k) {
        const int tt = w + 4 * k;          // wave-uniform
        const int kind = tt >> 4;          // 0=Q 1=K 2=V
        const int rr = tt & 15;
        const int ct = rr >> 1;
        const int half = rr & 1;

        const f16* WF = (kind == 0) ? WqF : ((kind == 1) ? WkF : WvF);
        const f16* Bs = (kind == 0) ? Xs : As;
        const float* bias = (kind == 0) ? bq : ((kind == 1) ? bk : bv);
        const float bscale = (kind == 0) ? LOG2E : 1.0f;

        // A-frags: contiguous 1KB per wave-load from frag-layout WF
        const f16* ap = WF + (size_t)(ct * 16) * 512 + (size_t)lane * 8;
        const f16* bp = Bs + (half * 32 + l31) * 256 + hib;

        f32x16 acc;
#pragma unroll
        for (int r = 0; r < 16; ++r) acc[r] = 0.0f;
#pragma unroll
        for (int ks = 0; ks < 16; ++ks) {
            f16x8 afr = *(const f16x8*)(ap + ks * 512);
            f16x8 bfr = *(const f16x8*)(bp + ((ks ^ xu) << 4));
            acc = __builtin_amdgcn_mfma_f32_32x32x16_f16(afr, bfr, acc, 0, 0, 0);
        }

        f16* st = Ostage[w];
        if (kind < 2) {
            // stage row-major [n32][c32]
#pragma unroll
            for (int g = 0; g < 4; ++g) {
                f32x4 bb = *(const f32x4*)(bias + ct * 32 + 4 * hi + 8 * g);
                f16x4 pk;
#pragma unroll
                for (int e = 0; e < 4; ++e) pk[e] = (f16)(acc[4 * g + e] + bb[e] * bscale);
                *(f16x4*)(st + l31 * 32 + 4 * hi + 8 * g) = pk;
            }
            if (kind == 0) {
                // Q dump: 2 wave-stores, 16 rows x 64B dense segments each
                f16* dst = qT + ((size_t)b * NPIX + i0 + half * 32) * CDIM + ct * 32;
#pragma unroll
                for (int d = 0; d < 2; ++d) {
                    int row = d * 16 + (lane >> 2);
                    int c8  = (lane & 3) * 8;
                    f16x8 v = *(const f16x8*)(st + row * 32 + c8);
                    *(f16x8*)(dst + (size_t)row * CDIM + c8) = v;
                }
            } else {
                // K dump -> chunk-major kC[b][kc][j][8]: per store 4 kc x 16 j (256B segs)
                const int j0 = i0 + half * 32;
                f16* dstb = kC + (size_t)b * CDIM * NPIX;
#pragma unroll
                for (int d = 0; d < 2; ++d) {
                    int row = d * 16 + (lane >> 2);   // j-local 0..31
                    int kl  = lane & 3;               // c-chunk-local 0..3
                    f16x8 v = *(const f16x8*)(st + row * 32 + kl * 8);
                    *(f16x8*)(dstb + ((size_t)(ct * 4 + kl) * NPIX + j0 + row) * 8) = v;
                }
            }
        } else {
            // stage [c32][j32] (rows 64B), dump 16B chunks (lanes 0-3 = one 64B c-row)
#pragma unroll
            for (int g = 0; g < 4; ++g) {
                f32x4 bb = *(const f32x4*)(bias + ct * 32 + 4 * hi + 8 * g);
#pragma unroll
                for (int e = 0; e < 4; ++e) {
                    int c31 = 4 * hi + 8 * g + e;
                    st[c31 * 32 + l31] = (f16)(acc[4 * g + e] + bb[e]);
                }
            }
            const int j0 = i0 + half * 32;
            f16* dstb = vW + (size_t)b * CDIM * NPIX + (size_t)(ct * 32) * NPIX + j0;
#pragma unroll
            for (int d = 0; d < 2; ++d) {
                int chunk = d * 64 + lane;          // 0..127
                int c31 = chunk >> 2, jch = chunk & 3;
                *(f16x8*)(dstb + (size_t)c31 * NPIX + jch * 8) =
                    *(const f16x8*)(st + chunk * 8);
            }
        }
    }
}

// ---------------- kernel 2: flash attention + residual ----------------
// 512 threads = 8 waves = 4 i-strips x 2 j-halves; grid 256 = 1 block/CU.
// Double-buffered 2x(K 32KB + V 32KB) LDS; one barrier per iter.
// NEW: conflict-free ds_read_b128 for BOTH operands via full-32-distinct chunk
// positions (empirical rule from R0/R3/R5 ledger), with LEAN addressing:
//  K: LDS transposed (row = kc*2+jhalf, pos = l31) -> 1 base + ks*2048B immediates,
//     staged coalesced from chunk-major kC.
//  V: row = (c>>5)*8+(c&7), pos = ((l31>>3)<<3)|(jc^(l31&7)) -> 2 bases + ct*2048 imm.
__global__ __launch_bounds__(512, 2)
void attn_kernel(const f16* __restrict__ qT, const f16* __restrict__ kC,
                 const f16* __restrict__ vW, const float* __restrict__ x,
                 float* __restrict__ out) {
    extern __shared__ unsigned char smem[];   // 131584 B: 2x65536 buffers; epilogue overlay

    const int b    = blockIdx.x & 7;          // batch -> XCD pinning for K/V L2 reuse
    const int i0   = (blockIdx.x >> 3) * 128;
    const int t    = threadIdx.x;             // 0..511
    const int w    = t >> 6;
    const int lane = t & 63;
    const int l31  = lane & 31;
    const int hi   = lane >> 5;
    const int iw   = (w & 3) * 32;            // i-strip
    const int jh   = (w >> 2) * 32;           // j-half
    const int jh8  = (w >> 2) * 4;            // j-half in 8-col chunks
    const int ig   = i0 + iw + l31;

    // Q B-frags in registers: B[k=c][n=i], n = l31, k-offset 8*hi
    f16x8 qf[16];
    {
        const f16* qp = qT + ((size_t)b * NPIX + ig) * CDIM + hi * 8;
#pragma unroll
        for (int ks = 0; ks < 16; ++ks) qf[ks] = *(const f16x8*)(qp + ks * 16);
    }

    // K read: addr = kbase + ks*1024 (f16); row = 4ks+2hi+jh5 holds (kc=2ks+hi, jhalf),
    // pos = l31 -> 32 distinct positions, conflict-free, all-immediate offsets.
    const int kbase = hi * 512 + (jh >> 5) * 256 + l31 * 8;
    // V read: row = ct*8+(l31&7), pos = ((l31>>3)<<3)|(jc^(l31&7)) -> 32 distinct.
    int vp2o[2];
    {
        int vbase = 16384 + (l31 & 7) * 256 + ((l31 >> 3) << 6);
#pragma unroll
        for (int kj = 0; kj < 2; ++kj)
            vp2o[kj] = vbase + (((jh8 + 2 * kj + hi) ^ (l31 & 7)) << 3);
    }

    f32x16 acc[8];
#pragma unroll
    for (int ct = 0; ct < 8; ++ct)
#pragma unroll
        for (int r = 0; r < 16; ++r) acc[ct][r] = 0.0f;
    float lrun = 0.0f;

    const f16* kb = kC + (size_t)b * CDIM * NPIX;   // chunk-major [kc][j][8]
    const f16* vb = vW + (size_t)b * CDIM * NPIX;
    f16* lds0 = (f16*)smem;
    const int wub = (t & ~63) * 8;            // wave-uniform staging base (f16 units)

    // prologue: stage tile 0 into buffer 0
    {
#pragma unroll
        for (int rep = 0; rep < 4; ++rep) {
            int slot = t + rep * 512;         // 0..2047 = LDS 16B-chunk index
            // K: row = slot>>5 = kc*2+jhalf, pos = slot&31 = j-local; src contiguous in j
            int kc = slot >> 6, jhalf = (slot >> 5) & 1, pj = slot & 31;
            gl2lds16(kb + ((size_t)kc * NPIX + jhalf * 32 + pj) * 8,
                     lds0 + wub + rep * 4096);
            // V: invert (row,pos) -> (c, jc)
            int row = slot >> 5, pv = slot & 31;
            int vc = ((row >> 3) << 5) | (((pv >> 3) & 3) << 3) | (row & 7);
            int vjc = (pv & 7) ^ (row & 7);
            gl2lds16(vb + (size_t)vc * NPIX + vjc * 8,
                     lds0 + 16384 + wub + rep * 4096);
        }
    }

    union Q4 { f16x4 h; unsigned int u[2]; };
    union B8 { f16x8 h; unsigned int u[4]; };

#pragma unroll 1
    for (int jt = 0; jt < 64; ++jt) {
        const int p = jt & 1;
        __syncthreads();   // drains vmcnt -> buffer p DMA complete; buffer p^1 free to restage

        if (jt < 63) {     // prefetch next tile into p^1; lands during this compute phase
            const int j0n = (jt + 1) * 64;
            f16* dstb = lds0 + (p ^ 1) * 32768;
#pragma unroll
            for (int rep = 0; rep < 4; ++rep) {
                int slot = t + rep * 512;
                int kc = slot >> 6, jhalf = (slot >> 5) & 1, pj = slot & 31;
                gl2lds16(kb + ((size_t)kc * NPIX + j0n + jhalf * 32 + pj) * 8,
                         dstb + wub + rep * 4096);
                int row = slot >> 5, pv = slot & 31;
                int vc = ((row >> 3) << 5) | (((pv >> 3) & 3) << 3) | (row & 7);
                int vjc = (pv & 7) ^ (row & 7);
                gl2lds16(vb + (size_t)vc * NPIX + j0n + vjc * 8,
                         dstb + 16384 + wub + rep * 4096);
            }
        }

        const f16* L = lds0 + p * 32768;

        // S^T (32 j-half x 32 i) = K Q^T, C-init = -SOFF folds the exp2 offset
        f32x16 s;
#pragma unroll
        for (int r = 0; r < 16; ++r) s[r] = -SOFF;
#pragma unroll
        for (int ks = 0; ks < 16; ++ks)
            s = __builtin_amdgcn_mfma_f32_32x32x16_f16(
                *(const f16x8*)(L + kbase + ks * 1024), qf[ks], s, 0, 0, 0);

        // fixed-offset softmax numerator; row-sum accumulates in-register
        Q4 ownq[4];
        float rtot = 0.0f;
#pragma unroll
        for (int g = 0; g < 4; ++g) {
            float p0 = __builtin_amdgcn_exp2f(s[4 * g + 0]);
            float p1 = __builtin_amdgcn_exp2f(s[4 * g + 1]);
            float p2 = __builtin_amdgcn_exp2f(s[4 * g + 2]);
            float p3 = __builtin_amdgcn_exp2f(s[4 * g + 3]);
            rtot += (p0 + p1) + (p2 + p3);
            ownq[g].h[0] = (f16)p0; ownq[g].h[1] = (f16)p1;
            ownq[g].h[2] = (f16)p2; ownq[g].h[3] = (f16)p3;
        }
        lrun += rtot;

        // P: C-layout -> B-layout via lane^32 quad exchange
        f16x8 pb[2];
#pragma unroll
        for (int kj = 0; kj < 2; ++kj) {
            int sidx = 2 * kj + 1 - hi;
            int oidx = 2 * kj + hi;
            unsigned int s0 = ownq[sidx].u[0], s1 = ownq[sidx].u[1];
            unsigned int r0 = (unsigned int)__shfl_xor((int)s0, 32);
            unsigned int r1 = (unsigned int)__shfl_xor((int)s1, 32);
            B8 bb;
            bb.u[0] = hi ? r0 : ownq[oidx].u[0];
            bb.u[1] = hi ? r1 : ownq[oidx].u[1];
            bb.u[2] = hi ? ownq[oidx].u[0] : r0;
            bb.u[3] = hi ? ownq[oidx].u[1] : r1;
            pb[kj] = bb.h;
        }

        // O += V P^T
#pragma unroll
        for (int ct = 0; ct < 8; ++ct) {
            acc[ct] = __builtin_amdgcn_mfma_f32_32x32x16_f16(
                *(const f16x8*)(L + vp2o[0] + ct * 2048), pb[0], acc[ct], 0, 0, 0);
            acc[ct] = __builtin_amdgcn_mfma_f32_32x32x16_f16(
                *(const f16x8*)(L + vp2o[1] + ct * 2048), pb[1], acc[ct], 0, 0, 0);
        }
    }

    // ---- epilogue: merge j-half pairs (w <-> w+4), coalesced residual store ----
    float lsum = lrun + __shfl_xor(lrun, 32);
    __syncthreads();
    float* Obuf = (float*)smem;               // overlay: 4 x 8192 floats = 128 KB
    float* Ls   = (float*)(smem + 131072);    // 128 floats
    if (w >= 4) {
        float* ob = Obuf + (w - 4) * 8192;    // [c][i32]
#pragma unroll
        for (int ct = 0; ct < 8; ++ct)
#pragma unroll
            for (int r = 0; r < 16; ++r) {
                int c = ct * 32 + (r & 3) + 8 * (r >> 2) + 4 * hi;
                ob[c * 32 + l31] = acc[ct][r];
            }
        if (hi == 0) Ls[(w - 4) * 32 + l31] = lsum;
    }
    __syncthreads();
    if (w < 4) {
        const float ltot = lsum + Ls[w * 32 + l31];
        const float invl = 1.0f / ltot;
        const float* po = Obuf + w * 8192;
        const float* xb = x + (size_t)b * CDIM * NPIX + i0 + iw;
        float* og = out + (size_t)b * CDIM * NPIX + i0 + iw;
#pragma unroll
        for (int ct = 0; ct < 8; ++ct)
#pragma unroll
            for (int r = 0; r < 16; ++r) {
                int c = ct * 32 + (r & 3) + 8 * (r >> 2) + 4 * hi;
                size_t off = (size_t)c * NPIX + l31;
                og[off] = (acc[ct][r] + po[c * 32 + l31]) * invl + xb[off];
            }
    }
}

extern "C" void kernel_launch(void* const* d_in, const int* in_sizes, int n_in,
                              void* d_out, int out_size, void* d_ws, size_t ws_size,
                              hipStream_t stream) {
    const float* x    = (const float*)d_in[0];
    const float* attr = (const float*)d_in[1];
    const float* Wq   = (const float*)d_in[2];
    const float* bq   = (const float*)d_in[3];
    const float* Wk   = (const float*)d_in[4];
    const float* bk   = (const float*)d_in[5];
    const float* Wv   = (const float*)d_in[6];
    const float* bv   = (const float*)d_in[7];
    float* out = (float*)d_out;

    // workspace layout (~48.4 MB)
    char* ws = (char*)d_ws;
    const size_t qkv_bytes = (size_t)8 * NPIX * CDIM * sizeof(f16);  // 16 MB each
    f16* qT   = (f16*)ws;
    f16* kC   = (f16*)(ws + qkv_bytes);
    f16* vW   = (f16*)(ws + 2 * qkv_bytes);
    f16* WqF  = (f16*)(ws + 3 * qkv_bytes);
    f16* WkF  = WqF + 65536;
    f16* WvF  = WkF + 65536;

    (void)hipFuncSetAttribute((const void*)attn_kernel,
                              hipFuncAttributeMaxDynamicSharedMemorySize, 131584);

    convert_w_kernel<<<96, 256, 0, stream>>>(Wq, Wk, Wv, WqF, WkF, WvF);
    proj_kernel<<<512, 256, 0, stream>>>(x, attr, WqF, bq, WkF, bk, WvF, bv, qT, kC, vW);
    attn_kernel<<<256, 512, 131584, stream>>>(qT, kC, vW, x, out);
}